// Round 7
// baseline (149.333 us; speedup 1.0000x reference)
//
#include <hip/hip_runtime.h>

// NTN: out[n,k] = relu( cos(x1 @ W1[k], x2 @ W2[k]) + [x1,x2]·V[k] + b[k] )
// N=32768, D=128, K=16.
// R10 = R3's proven nt=2 math, with W split across two pipes.
// Model from R3..R9: per-CU pipe budget LDS 42% + VALU 30% + MFMA 27% ~= 100%
// and occupancy x2 (R6), counted vmcnt (R7), reg-ILP (R9) all null/worse ->
// pipes effectively serialized; only reducing/moving pipe WORK helps.
//  - side-0 W halves staged to LDS (16KB chunks, 2-slot ping-pong, 32KB LDS);
//    side-1 W frags read DIRECT from global wsW (L2-resident 1MB, idle VMEM
//    pipe) with 1-et lookahead. LDS-pipe work halves.
//  - grid 1024 = 256 rb x 4 kq (128 rows/block), XCD-major: 4 kq-blocks of an
//    rb on one XCD (X re-reads L2-hit, out 16B quarters merge).
//  - 32KB LDS + ~160 VGPR -> 3 blocks/CU = 12 waves/CU.
//  - folds as f32x2 (v_pk_fma_f32 candidates) -> fold VALU halves.
//  - launch_bounds(256,1): cap 256 (R8 lesson: (256,2) caps at 128 and spills).

typedef __attribute__((ext_vector_type(8))) __bf16 bf16x8;
typedef __attribute__((ext_vector_type(8))) unsigned short us8;
typedef __attribute__((ext_vector_type(4))) float f32x4;
typedef __attribute__((ext_vector_type(2))) float f32x2;

static __device__ __forceinline__ unsigned short f2bf(float f) {
  unsigned u = __float_as_uint(f);
  u += 0x7FFFu + ((u >> 16) & 1u);   // round-to-nearest-even
  return (unsigned short)(u >> 16);
}

static __device__ __forceinline__ bf16x8 as_bf(us8 u) {
  bf16x8 r;
  __builtin_memcpy(&r, &u, sizeof(r));
  return r;
}

// ---------------- prep (UNCHANGED) ----------------
// wsW: 32 chunks (cc = k*2 + h) of 2048 16B-units.
//   unit u: side=(u>>10)&1, et'=(u>>8)&3, s=(u>>6)&3, lane=u&63.
//   frag[j] = W_side[k][d = s*32 + (lane>>4)*8 + j][e = (h*4+et')*16 + (lane&15)]
// wsV: unit cs*64+lane: frag[j] = V[lane&15][c = cs*32 + (lane>>4)*8 + j]
__global__ void ntn_prep(const float* __restrict__ W1, const float* __restrict__ W2,
                         const float* __restrict__ V,
                         unsigned short* __restrict__ wsW, unsigned short* __restrict__ wsV) {
  int t = blockIdx.x * 256 + threadIdx.x;
  if (t < 65536) {
    int u = t & 2047;
    int lane = u & 63, s = (u >> 6) & 3, et2 = (u >> 8) & 3, side = (u >> 10) & 1;
    int cc = t >> 11, h = cc & 1, k = cc >> 1;
    int q = lane >> 4, l15 = lane & 15;
    int et = h * 4 + et2;
    const float* W = side ? W2 : W1;
    const float* src = W + k * 16384 + (s * 32 + q * 8) * 128 + (et * 16 + l15);
    us8 r;
#pragma unroll
    for (int j = 0; j < 8; ++j) r[j] = f2bf(src[j * 128]);
    *(us8*)(wsW + (size_t)t * 8) = r;
  } else if (t < 66048) {
    int u = t - 65536;
    int lane = u & 63, cs = u >> 6;
    int q = lane >> 4, l15 = lane & 15;
    const float* src = V + l15 * 256 + cs * 32 + q * 8;
    us8 r;
#pragma unroll
    for (int j = 0; j < 8; ++j) r[j] = f2bf(src[j]);
    *(us8*)(wsV + (size_t)u * 8) = r;
  }
}

// ---------------- main ----------------
__global__ __launch_bounds__(256, 1) void ntn_main(
    const float* __restrict__ x1, const float* __restrict__ x2,
    const float* __restrict__ b,
    const unsigned short* __restrict__ wsW, const unsigned short* __restrict__ wsV,
    float* __restrict__ out) {
  __shared__ uint4 ldsH[2][1024];   // two 16KB side-0 half-chunk slots = 32KB

  const int tid = threadIdx.x;
  const int lane = tid & 63, wave = tid >> 6;
  const int q = lane >> 4, l15 = lane & 15;

  // XCD-major mapping: bi&7 = XCD. Each XCD: 128 blocks = 32 rb x 4 kq,
  // 4 kq-blocks of one rb adjacent.
  const int bi = blockIdx.x;
  const int xcd = bi & 7, jj = bi >> 3;   // jj 0..127
  const int rb = xcd * 32 + (jj >> 2);    // 0..255: 128-row group
  const int kq = jj & 3;                  // k range [kq*4, kq*4+4)
  const int rowbase = rb * 128 + wave * 32;

  const f32x4 zero4 = {0.f, 0.f, 0.f, 0.f};

  // async stage of one 16KB side-0 half (4 glds x 64 lanes x 16B per wave)
  auto stage = [&](int cc, int slot) {
    const unsigned short* src = wsW + ((size_t)cc * 2048 + wave * 256 + lane) * 8;
    uint4* dst = &ldsH[slot][wave * 256];
#pragma unroll
    for (int i = 0; i < 4; ++i)
      __builtin_amdgcn_global_load_lds(
          (__attribute__((address_space(1))) void*)(void*)(src + i * 512),
          (__attribute__((address_space(3))) void*)(dst + i * 64), 16, 0, 0);
  };

  stage(kq * 8, 0);   // first chunk of our k range (side 0)

  // ---- X fragments (B-operand), bf16, k-invariant, in registers ----
  bf16x8 xb[2][2][4];
#pragma unroll
  for (int side = 0; side < 2; ++side) {
    const float* xp0 = side ? x2 : x1;
#pragma unroll
    for (int nt = 0; nt < 2; ++nt) {
#pragma unroll
      for (int s = 0; s < 4; ++s) {
        const float* p = xp0 + (size_t)(rowbase + nt * 16 + l15) * 128 + s * 32 + q * 8;
        float4 v0 = *(const float4*)p;
        float4 v1 = *(const float4*)(p + 4);
        us8 uu;
        uu[0] = f2bf(v0.x); uu[1] = f2bf(v0.y); uu[2] = f2bf(v0.z); uu[3] = f2bf(v0.w);
        uu[4] = f2bf(v1.x); uu[5] = f2bf(v1.y); uu[6] = f2bf(v1.z); uu[7] = f2bf(v1.w);
        xb[side][nt][s] = as_bf(uu);
      }
    }
  }

  // ---- part2 + b via MFMA (A = V frags; B = X frags), kept in registers ----
  f32x4 accP[2];
  {
    bf16x8 vf[8];
#pragma unroll
    for (int cs = 0; cs < 8; ++cs)
      vf[cs] = as_bf(*(const us8*)(wsV + (size_t)(cs * 64 + lane) * 8));
    float4 bv = *(const float4*)(b + q * 4);
#pragma unroll
    for (int nt = 0; nt < 2; ++nt) {
      f32x4 a = zero4;
#pragma unroll
      for (int cs = 0; cs < 8; ++cs)
        a = __builtin_amdgcn_mfma_f32_16x16x32_bf16(vf[cs], xb[cs >> 2][nt][cs & 3], a, 0, 0, 0);
      a.x += bv.x; a.y += bv.y; a.z += bv.z; a.w += bv.w;
      accP[nt] = a;   // lane quad q holds part2+b for k = q*4 + reg
    }
  }

  // f32x2 fold accumulators (pk-fma candidates)
  f32x2 nmv[2], q1v[2], q2v[2];
#pragma unroll
  for (int nt = 0; nt < 2; ++nt) {
    nmv[nt] = (f32x2){0.f, 0.f}; q1v[nt] = (f32x2){0.f, 0.f}; q2v[nt] = (f32x2){0.f, 0.f};
  }

  // compute one chunk: wa (side0) from LDS slot; wb (side1) DIRECT from global
  // wsW with 1-et lookahead. Folds into f32x2 accumulators.
  auto compute = [&](int slot, int cc) {
    const unsigned short* wsrc = wsW + (size_t)cc * 16384 + 8192;  // side-1 base
    bf16x8 wbc[4], wbn[4];
#pragma unroll
    for (int s = 0; s < 4; ++s)
      wbc[s] = as_bf(*(const us8*)(wsrc + (size_t)(s * 64 + lane) * 8));
#pragma unroll
    for (int et = 0; et < 4; ++et) {
      if (et < 3) {
#pragma unroll
        for (int s = 0; s < 4; ++s)
          wbn[s] = as_bf(*(const us8*)(wsrc + (size_t)((et + 1) * 256 + s * 64 + lane) * 8));
      }
      bf16x8 wa[4];
#pragma unroll
      for (int s = 0; s < 4; ++s)
        wa[s] = as_bf(*(const us8*)&ldsH[slot][et * 256 + s * 64 + lane]);
#pragma unroll
      for (int nt = 0; nt < 2; ++nt) {
        f32x4 a1 = zero4, a2 = zero4;
#pragma unroll
        for (int s = 0; s < 4; ++s)
          a1 = __builtin_amdgcn_mfma_f32_16x16x32_bf16(wa[s], xb[0][nt][s], a1, 0, 0, 0);
#pragma unroll
        for (int s = 0; s < 4; ++s)
          a2 = __builtin_amdgcn_mfma_f32_16x16x32_bf16(wbc[s], xb[1][nt][s], a2, 0, 0, 0);
        f32x2 a1lo = {a1.x, a1.y}, a1hi = {a1.z, a1.w};
        f32x2 a2lo = {a2.x, a2.y}, a2hi = {a2.z, a2.w};
        nmv[nt] += a1lo * a2lo; nmv[nt] += a1hi * a2hi;
        q1v[nt] += a1lo * a1lo; q1v[nt] += a1hi * a1hi;
        q2v[nt] += a2lo * a2lo; q2v[nt] += a2hi * a2hi;
      }
#pragma unroll
      for (int s = 0; s < 4; ++s) wbc[s] = wbn[s];
    }
  };

#pragma unroll 1
  for (int kk = 0; kk < 4; ++kk) {
    const int cbase = kq * 8 + 2 * kk;
    __syncthreads();                       // side0 of chunk (kk,h=0) in slot0
    stage(cbase + 1, 1);
    compute(0, cbase);
    __syncthreads();                       // side0 of chunk (kk,h=1) in slot1
    if (kk < 3) stage(cbase + 2, 0);
    compute(1, cbase + 1);

    const int k = kq * 4 + kk;
    const int qo = k >> 2;                 // owning lane quad (== kq)
    const int r  = k & 3;                  // == kk
#pragma unroll
    for (int nt = 0; nt < 2; ++nt) {
      float n = nmv[nt].x + nmv[nt].y;
      float s1 = q1v[nt].x + q1v[nt].y;
      float s2 = q2v[nt].x + q2v[nt].y;
      n  += __shfl_xor(n, 16);  n  += __shfl_xor(n, 32);
      s1 += __shfl_xor(s1, 16); s1 += __shfl_xor(s1, 32);
      s2 += __shfl_xor(s2, 16); s2 += __shfl_xor(s2, 32);
      float d1 = fmaxf(sqrtf(s1), 1e-8f);
      float d2 = fmaxf(sqrtf(s2), 1e-8f);
      float p1 = n / (d1 * d2);
      float pc = (r == 0) ? accP[nt].x : (r == 1) ? accP[nt].y
               : (r == 2) ? accP[nt].z : accP[nt].w;
      if (q == qo)
        out[(size_t)(rowbase + nt * 16 + l15) * 16 + k] = fmaxf(p1 + pc, 0.f);
      nmv[nt] = (f32x2){0.f, 0.f}; q1v[nt] = (f32x2){0.f, 0.f}; q2v[nt] = (f32x2){0.f, 0.f};
    }
  }
}

extern "C" void kernel_launch(void* const* d_in, const int* in_sizes, int n_in,
                              void* d_out, int out_size, void* d_ws, size_t ws_size,
                              hipStream_t stream) {
  const float* x1 = (const float*)d_in[0];
  const float* x2 = (const float*)d_in[1];
  const float* W1 = (const float*)d_in[2];
  const float* W2 = (const float*)d_in[3];
  const float* V  = (const float*)d_in[4];
  const float* b  = (const float*)d_in[5];
  float* out = (float*)d_out;
  unsigned short* wsW = (unsigned short*)d_ws;
  unsigned short* wsV = wsW + (size_t)65536 * 8;   // 1MB offset

  ntn_prep<<<258, 256, 0, stream>>>(W1, W2, V, wsW, wsV);
  ntn_main<<<1024, 256, 0, stream>>>(x1, x2, b, wsW, wsV, out);
}

// Round 8
// 119.420 us; speedup vs baseline: 1.2505x; 1.2505x over previous
//
#include <hip/hip_runtime.h>

// NTN: out[n,k] = relu( cos(x1 @ W1[k], x2 @ W2[k]) + [x1,x2]·V[k] + b[k] )
// N=32768, D=128, K=16.
// R11 = R3 main kernel VERBATIM (49.4us champion; R4..R10 all neutral/worse)
//       + prep rewritten elementwise.
// Evidence: bench - main = 65-70us in EVERY round (R0:119.5-49.8, R6:124-57.5,
// R7:119.9-49.4, R9:139-70, R10:149-84). The old prep ran 66,048 threads
// (4 waves/CU!) each doing 8x 512B-strided HBM loads — latency-bound, ~tens
// of us. New prep: 1 f32 load -> 1 bf16 store per thread, 528,384 threads
// (2064 blocks), same output layout (e2 = t*8 + j index algebra).

typedef __attribute__((ext_vector_type(8))) __bf16 bf16x8;
typedef __attribute__((ext_vector_type(8))) unsigned short us8;
typedef __attribute__((ext_vector_type(4))) float f32x4;

static __device__ __forceinline__ unsigned short f2bf(float f) {
  unsigned u = __float_as_uint(f);
  u += 0x7FFFu + ((u >> 16) & 1u);   // round-to-nearest-even
  return (unsigned short)(u >> 16);
}

static __device__ __forceinline__ bf16x8 as_bf(us8 u) {
  bf16x8 r;
  __builtin_memcpy(&r, &u, sizeof(r));
  return r;
}

// ---------------- prep (elementwise rewrite; SAME output layout) ----------------
// wsW[t*8+j] = f2bf(W_side[k][d = s*32 + q*8 + j][e = (h*4+et')*16 + l15])
//   with t: u=t&2047, cc=t>>11; lane=u&63, s=(u>>6)&3, et'=(u>>8)&3,
//   side=(u>>10)&1; h=cc&1, k=cc>>1; q=lane>>4, l15=lane&15.
// wsV[u*8+j] = f2bf(V[l15*256 + cs*32 + q*8 + j]), u: lane=u&63, cs=u>>6.
__global__ void ntn_prep(const float* __restrict__ W1, const float* __restrict__ W2,
                         const float* __restrict__ V,
                         unsigned short* __restrict__ wsW, unsigned short* __restrict__ wsV) {
  int e2 = blockIdx.x * 256 + threadIdx.x;
  if (e2 < 524288) {
    int j = e2 & 7, t = e2 >> 3;
    int u = t & 2047, cc = t >> 11;
    int lane = u & 63, s = (u >> 6) & 3, et2 = (u >> 8) & 3, side = (u >> 10) & 1;
    int h = cc & 1, k = cc >> 1;
    int q = lane >> 4, l15 = lane & 15;
    int et = h * 4 + et2;
    const float* W = side ? W2 : W1;
    wsW[e2] = f2bf(W[k * 16384 + (s * 32 + q * 8 + j) * 128 + (et * 16 + l15)]);
  } else if (e2 < 528384) {
    int v2 = e2 - 524288;
    int j = v2 & 7, u = v2 >> 3;
    int lane = u & 63, cs = u >> 6;
    int q = lane >> 4, l15 = lane & 15;
    wsV[v2] = f2bf(V[l15 * 256 + cs * 32 + q * 8 + j]);
  }
}

// ---------------- main (R3 champion, VERBATIM) ----------------
__global__ __launch_bounds__(256, 2) void ntn_main(
    const float* __restrict__ x1, const float* __restrict__ x2,
    const float* __restrict__ b,
    const unsigned short* __restrict__ wsW, const unsigned short* __restrict__ wsV,
    float* __restrict__ out) {
  __shared__ uint4 ldsW[2][2048];   // two 32KB chunk slots = 64KB

  const int tid = threadIdx.x;
  const int lane = tid & 63, wave = tid >> 6;
  const int q = lane >> 4, l15 = lane & 15;
  const int kh = blockIdx.x & 1;          // k range [8kh, 8kh+8)
  const int rb = blockIdx.x >> 1;         // 128-row group
  const int rowbase = rb * 128 + wave * 32;

  const f32x4 zero4 = {0.f, 0.f, 0.f, 0.f};

  // async stage of one 32KB chunk into an LDS slot (8 glds x 64 lanes x 16B / wave)
  auto stage = [&](int cc, int slot) {
    const unsigned short* src = wsW + (size_t)cc * 16384 + (size_t)(wave * 512 + lane) * 8;
    uint4* dst = &ldsW[slot][wave * 512];
#pragma unroll
    for (int i = 0; i < 8; ++i)
      __builtin_amdgcn_global_load_lds(
          (__attribute__((address_space(1))) void*)(void*)(src + i * 512),
          (__attribute__((address_space(3))) void*)(dst + i * 64), 16, 0, 0);
  };

  stage(kh * 16, 0);   // first chunk of our k range

  // ---- X fragments (B-operand), bf16, k-invariant, in registers ----
  // frag[j] = X[row = rowbase + nt*16 + (lane&15)][d = s*32 + (lane>>4)*8 + j]
  bf16x8 xb[2][2][4];
#pragma unroll
  for (int side = 0; side < 2; ++side) {
    const float* xp0 = side ? x2 : x1;
#pragma unroll
    for (int nt = 0; nt < 2; ++nt) {
#pragma unroll
      for (int s = 0; s < 4; ++s) {
        const float* p = xp0 + (size_t)(rowbase + nt * 16 + l15) * 128 + s * 32 + q * 8;
        float4 v0 = *(const float4*)p;
        float4 v1 = *(const float4*)(p + 4);
        us8 uu;
        uu[0] = f2bf(v0.x); uu[1] = f2bf(v0.y); uu[2] = f2bf(v0.z); uu[3] = f2bf(v0.w);
        uu[4] = f2bf(v1.x); uu[5] = f2bf(v1.y); uu[6] = f2bf(v1.z); uu[7] = f2bf(v1.w);
        xb[side][nt][s] = as_bf(uu);
      }
    }
  }

  // ---- part2 + b via MFMA (A = V frags: M=k; B = X frags), kept in registers ----
  f32x4 accP[2];
  {
    bf16x8 vf[8];
#pragma unroll
    for (int cs = 0; cs < 8; ++cs)
      vf[cs] = as_bf(*(const us8*)(wsV + (size_t)(cs * 64 + lane) * 8));
    float4 bv = *(const float4*)(b + q * 4);
#pragma unroll
    for (int nt = 0; nt < 2; ++nt) {
      f32x4 a = zero4;
#pragma unroll
      for (int cs = 0; cs < 8; ++cs)
        a = __builtin_amdgcn_mfma_f32_16x16x32_bf16(vf[cs], xb[cs >> 2][nt][cs & 3], a, 0, 0, 0);
      a.x += bv.x; a.y += bv.y; a.z += bv.z; a.w += bv.w;
      accP[nt] = a;   // lane quad q holds part2+b for k = q*4 + reg
    }
  }

  float nm[2] = {0.f, 0.f}, q1[2] = {0.f, 0.f}, q2[2] = {0.f, 0.f};

  // compute one e-half (4 e-tiles, both sides) from an LDS slot, fold reductions
  auto compute = [&](int slot) {
#pragma unroll
    for (int et = 0; et < 4; ++et) {
      bf16x8 wa[4], wb[4];
#pragma unroll
      for (int s = 0; s < 4; ++s) {
        wa[s] = as_bf(*(const us8*)&ldsW[slot][et * 256 + s * 64 + lane]);
        wb[s] = as_bf(*(const us8*)&ldsW[slot][1024 + et * 256 + s * 64 + lane]);
      }
#pragma unroll
      for (int nt = 0; nt < 2; ++nt) {
        f32x4 a1 = zero4, a2 = zero4;
#pragma unroll
        for (int s = 0; s < 4; ++s)
          a1 = __builtin_amdgcn_mfma_f32_16x16x32_bf16(wa[s], xb[0][nt][s], a1, 0, 0, 0);
#pragma unroll
        for (int s = 0; s < 4; ++s)
          a2 = __builtin_amdgcn_mfma_f32_16x16x32_bf16(wb[s], xb[1][nt][s], a2, 0, 0, 0);
        nm[nt] += a1.x * a2.x + a1.y * a2.y + a1.z * a2.z + a1.w * a2.w;
        q1[nt] += a1.x * a1.x + a1.y * a1.y + a1.z * a1.z + a1.w * a1.w;
        q2[nt] += a2.x * a2.x + a2.y * a2.y + a2.z * a2.z + a2.w * a2.w;
      }
    }
  };

#pragma unroll 1
  for (int kk = 0; kk < 8; ++kk) {
    const int cbase = kh * 16 + 2 * kk;
    __syncthreads();                       // chunk (kk, h=0) in slot0; slot1 free
    stage(cbase + 1, 1);
    compute(0);
    __syncthreads();                       // chunk (kk, h=1) in slot1; slot0 free
    if (kk < 7) stage(cbase + 2, 0);
    compute(1);

    const int k = kh * 8 + kk;
    const int qo = k >> 2;                 // owning lane quad
    const int r  = k & 3;
#pragma unroll
    for (int nt = 0; nt < 2; ++nt) {
      float n = nm[nt], s1 = q1[nt], s2 = q2[nt];
      n  += __shfl_xor(n, 16);  n  += __shfl_xor(n, 32);
      s1 += __shfl_xor(s1, 16); s1 += __shfl_xor(s1, 32);
      s2 += __shfl_xor(s2, 16); s2 += __shfl_xor(s2, 32);
      float d1 = fmaxf(sqrtf(s1), 1e-8f);
      float d2 = fmaxf(sqrtf(s2), 1e-8f);
      float p1 = n / (d1 * d2);
      float pc = (r == 0) ? accP[nt].x : (r == 1) ? accP[nt].y
               : (r == 2) ? accP[nt].z : accP[nt].w;
      if (q == qo)
        out[(size_t)(rowbase + nt * 16 + l15) * 16 + k] = fmaxf(p1 + pc, 0.f);
      nm[nt] = 0.f; q1[nt] = 0.f; q2[nt] = 0.f;
    }
  }
}

extern "C" void kernel_launch(void* const* d_in, const int* in_sizes, int n_in,
                              void* d_out, int out_size, void* d_ws, size_t ws_size,
                              hipStream_t stream) {
  const float* x1 = (const float*)d_in[0];
  const float* x2 = (const float*)d_in[1];
  const float* W1 = (const float*)d_in[2];
  const float* W2 = (const float*)d_in[3];
  const float* V  = (const float*)d_in[4];
  const float* b  = (const float*)d_in[5];
  float* out = (float*)d_out;
  unsigned short* wsW = (unsigned short*)d_ws;
  unsigned short* wsV = wsW + (size_t)65536 * 8;   // 1MB offset

  ntn_prep<<<2064, 256, 0, stream>>>(W1, W2, V, wsW, wsV);
  ntn_main<<<512, 256, 0, stream>>>(x1, x2, b, wsW, wsV, out);
}